// Round 3
// baseline (9234.698 us; speedup 1.0000x reference)
//
#include <hip/hip_runtime.h>
#include <cmath>

typedef __bf16 bf16x8 __attribute__((ext_vector_type(8)));
typedef float  f32x4  __attribute__((ext_vector_type(4)));
typedef unsigned int u32;
typedef unsigned long long u64;
typedef u64 u64x2 __attribute__((ext_vector_type(2)));

#define T_STEPS 1024
#define I_DIM   256
#define H_DIM   512
#define B_TOT   64
#define NBT     4     // batch tiles
#define NCT     32    // column tiles
#define BT      16    // batches per tile
#define CT      16    // columns per gate per WG
#define FDOM    64    // ints per flag domain (256B; 32 used, one 128B line)
#define HB_P    (NBT * BT * H_DIM)   // bf16 elems per parity buffer

__device__ __forceinline__ f32x4 mfma16(bf16x8 a, bf16x8 b, f32x4 c) {
    return __builtin_amdgcn_mfma_f32_16x16x32_bf16(a, b, c, 0, 0, 0);
}

// two float4 registers -> bf16x8 A-fragment (pure VALU, no loads)
__device__ __forceinline__ bf16x8 cvt8r(float4 a, float4 b) {
    bf16x8 f;
    f[0] = (__bf16)a.x; f[1] = (__bf16)a.y; f[2] = (__bf16)a.z; f[3] = (__bf16)a.w;
    f[4] = (__bf16)b.x; f[5] = (__bf16)b.y; f[6] = (__bf16)b.z; f[7] = (__bf16)b.w;
    return f;
}

// relaxed agent-scope primitives (serviced at the device coherence point)
__device__ __forceinline__ int ld_flag(const int* p) {
    return __hip_atomic_load(p, __ATOMIC_RELAXED, __HIP_MEMORY_SCOPE_AGENT);
}
__device__ __forceinline__ void st_flag(int* p, int v) {
    __hip_atomic_store(p, v, __ATOMIC_RELAXED, __HIP_MEMORY_SCOPE_AGENT);
}
__device__ __forceinline__ void st_u32(u32* p, u32 v) {
    __hip_atomic_store(p, v, __ATOMIC_RELAXED, __HIP_MEMORY_SCOPE_AGENT);
}
__device__ __forceinline__ bf16x8 ld_frag16(const __bf16* p) {
    u64x2 v;
    v.x = __hip_atomic_load((const u64*)p,     __ATOMIC_RELAXED, __HIP_MEMORY_SCOPE_AGENT);
    v.y = __hip_atomic_load((const u64*)p + 1, __ATOMIC_RELAXED, __HIP_MEMORY_SCOPE_AGENT);
    return __builtin_bit_cast(bf16x8, v);
}

// narrow coalesced detect: all 32 per-WG flags of this domain (one 128B line)
__device__ __forceinline__ void wait32(const int* fdom, int target) {
    const int* p = fdom + (threadIdx.x & 31);
    for (int g = 0; g < (1 << 22); ++g) {
        int v = ld_flag(p);
        if (__ballot(v >= target) == ~0ull) break;
    }
    asm volatile("" ::: "memory");   // keep data loads below the poll
}

// hardware-complete drain of stores + LDS writes; compiler memory fence
__device__ __forceinline__ void drain_all() {
    asm volatile("s_waitcnt vmcnt(0) lgkmcnt(0)" ::: "memory");
}

// Persistent wave-specialized GRU. Grid: 128 WGs = 4 batch-tiles x 32 col-tiles,
// 256 thr (4 waves). Roles: w0=R (full-K r, publishes r*h), w1=Z (full-K z -> LDS),
// w2=H1 (h~ partial, K low half -> LDS), w3=H2+finish (h~ high half, tanh, blend,
// publishes h, out[]). Protocol per exchange: stores -> vmcnt drain -> 1-line flag;
// consumers: narrow 32-flag poll -> one-shot frag loads.
__global__ __launch_bounds__(256, 1) void gru_persist(
    const float* __restrict__ xs,
    const float* __restrict__ Wz, const float* __restrict__ bz,
    const float* __restrict__ Wr, const float* __restrict__ br,
    const float* __restrict__ Wh, const float* __restrict__ bh,
    float* __restrict__ out,
    __bf16* hbuf, __bf16* rhbuf, int* flag_h, int* flag_r)
{
    const int bid  = blockIdx.x;
    const int i    = bid & (NBT - 1);
    const int j    = bid >> 2;
    const int tid  = threadIdx.x;
    const int w    = tid >> 6;
    const int lane = tid & 63;
    const int q    = lane >> 4;
    const int ln   = lane & 15;
    const int cb   = j * CT;

    __shared__ float zL[16][17];    // z gate, wave1 -> wave3
    __shared__ float pL[16][17];    // h~ partial, wave2 -> wave3
    __shared__ float hpL[16][17];   // f32 h_prev, wave3 -> wave0 (cross-step)

    const float* xrow = xs + (size_t)(i * BT + ln) * T_STEPS * I_DIM;
    int* fh_dom = flag_h + i * FDOM;
    int* fr_dom = flag_r + i * FDOM;
    int* my_fh  = fh_dom + j;
    int* my_fr  = fr_dom + j;

    if (w == 0) {
        // ================= wave 0: R gate, publishes r*h =================
        bf16x8 WB[24];
        #pragma unroll
        for (int s = 0; s < 24; ++s) {
            int krow = s * 32 + q * 8;
            bf16x8 f;
            #pragma unroll
            for (int jj = 0; jj < 8; ++jj) f[jj] = (__bf16)Wr[(krow + jj) * H_DIM + cb + ln];
            WB[s] = f;
        }
        const float bc = br[cb + ln];
        float4 xst[16];
        #pragma unroll
        for (int c = 0; c < 8; ++c) {
            xst[2*c]   = *(const float4*)(xrow + c * 32 + q * 8);
            xst[2*c+1] = *(const float4*)(xrow + c * 32 + q * 8 + 4);
        }
        for (int t = 0; t < T_STEPS; ++t) {
            const int p = t & 1, pp = p ^ 1;
            bf16x8 xfr[8];
            #pragma unroll
            for (int c = 0; c < 8; ++c) xfr[c] = cvt8r(xst[2*c], xst[2*c+1]);  // xst dies

            wait32(fh_dom, t);
            const __bf16* hb = hbuf + pp * HB_P + i * (BT * H_DIM) + ln * H_DIM;
            bf16x8 hf[16];
            #pragma unroll
            for (int s = 0; s < 16; ++s) hf[s] = ld_frag16(hb + s * 32 + q * 8);

            f32x4 a0 = {0,0,0,0}, a1 = {0,0,0,0};
            #pragma unroll
            for (int c = 0; c < 8; ++c) {      // x-part overlaps h-frag flight
                if (c & 1) a1 = mfma16(xfr[c], WB[c], a1);
                else       a0 = mfma16(xfr[c], WB[c], a0);
            }
            #pragma unroll
            for (int s = 0; s < 16; ++s) {
                if (s & 1) a1 = mfma16(hf[s], WB[8 + s], a1);
                else       a0 = mfma16(hf[s], WB[8 + s], a0);
            }
            __bf16* rbase = rhbuf + p * HB_P + i * (BT * H_DIM);
            #pragma unroll
            for (int r4 = 0; r4 < 4; ++r4) {
                int row = q * 4 + r4;
                float pr = a0[r4] + a1[r4] + bc;
                float rv = 1.0f / (1.0f + __expf(-pr));
                float rh = rv * hpL[row][ln];
                unsigned short v16 = __builtin_bit_cast(unsigned short, (__bf16)rh);
                unsigned short nb  = (unsigned short)__shfl((int)v16, lane + 1);
                if (!(ln & 1))
                    st_u32((u32*)(rbase + row * H_DIM + cb + ln), (u32)v16 | ((u32)nb << 16));
            }
            __syncthreads();                   // BARR_A (auto vmcnt drain covers rh stores)
            if (lane == 0) st_flag(my_fr, t + 1);
            {
                const float* xp = xrow + (size_t)((t + 1 < T_STEPS) ? t + 1 : t) * I_DIM;
                #pragma unroll
                for (int c = 0; c < 8; ++c) {
                    xst[2*c]   = *(const float4*)(xp + c * 32 + q * 8);
                    xst[2*c+1] = *(const float4*)(xp + c * 32 + q * 8 + 4);
                }
            }
            __syncthreads();                   // BARR_B
        }
    } else if (w == 1) {
        // ================= wave 1: Z gate -> LDS =================
        bf16x8 WB[24];
        #pragma unroll
        for (int s = 0; s < 24; ++s) {
            int krow = s * 32 + q * 8;
            bf16x8 f;
            #pragma unroll
            for (int jj = 0; jj < 8; ++jj) f[jj] = (__bf16)Wz[(krow + jj) * H_DIM + cb + ln];
            WB[s] = f;
        }
        const float bc = bz[cb + ln];
        float4 xst[16];
        #pragma unroll
        for (int c = 0; c < 8; ++c) {
            xst[2*c]   = *(const float4*)(xrow + c * 32 + q * 8);
            xst[2*c+1] = *(const float4*)(xrow + c * 32 + q * 8 + 4);
        }
        for (int t = 0; t < T_STEPS; ++t) {
            const int pp = (t & 1) ^ 1;
            bf16x8 xfr[8];
            #pragma unroll
            for (int c = 0; c < 8; ++c) xfr[c] = cvt8r(xst[2*c], xst[2*c+1]);

            wait32(fh_dom, t);
            const __bf16* hb = hbuf + pp * HB_P + i * (BT * H_DIM) + ln * H_DIM;
            bf16x8 hf[16];
            #pragma unroll
            for (int s = 0; s < 16; ++s) hf[s] = ld_frag16(hb + s * 32 + q * 8);

            __syncthreads();                   // BARR_A (auto drain: h-loads complete)

            f32x4 a0 = {0,0,0,0}, a1 = {0,0,0,0};
            #pragma unroll
            for (int c = 0; c < 8; ++c) {
                if (c & 1) a1 = mfma16(xfr[c], WB[c], a1);
                else       a0 = mfma16(xfr[c], WB[c], a0);
            }
            #pragma unroll
            for (int s = 0; s < 16; ++s) {
                if (s & 1) a1 = mfma16(hf[s], WB[8 + s], a1);
                else       a0 = mfma16(hf[s], WB[8 + s], a0);
            }
            #pragma unroll
            for (int r4 = 0; r4 < 4; ++r4) {
                float pz = a0[r4] + a1[r4] + bc;
                zL[q * 4 + r4][ln] = 1.0f / (1.0f + __expf(-pz));
            }
            __syncthreads();                   // BARR_B (auto lgkm drain: z visible)
            {
                const float* xp = xrow + (size_t)((t + 1 < T_STEPS) ? t + 1 : t) * I_DIM;
                #pragma unroll
                for (int c = 0; c < 8; ++c) {
                    xst[2*c]   = *(const float4*)(xp + c * 32 + q * 8);
                    xst[2*c+1] = *(const float4*)(xp + c * 32 + q * 8 + 4);
                }
            }
        }
    } else if (w == 2) {
        // ================= wave 2: h~ partial (x chunks 0-3, rh chunks 8-15) ======
        bf16x8 WB[12];
        #pragma unroll
        for (int c = 0; c < 4; ++c) {
            int krow = c * 32 + q * 8;
            bf16x8 f;
            #pragma unroll
            for (int jj = 0; jj < 8; ++jj) f[jj] = (__bf16)Wh[(krow + jj) * H_DIM + cb + ln];
            WB[c] = f;
        }
        #pragma unroll
        for (int s = 0; s < 8; ++s) {
            int krow = (8 + s) * 32 + q * 8;
            bf16x8 f;
            #pragma unroll
            for (int jj = 0; jj < 8; ++jj) f[jj] = (__bf16)Wh[(krow + jj) * H_DIM + cb + ln];
            WB[4 + s] = f;
        }
        float4 xst[8];
        #pragma unroll
        for (int c = 0; c < 4; ++c) {
            xst[2*c]   = *(const float4*)(xrow + c * 32 + q * 8);
            xst[2*c+1] = *(const float4*)(xrow + c * 32 + q * 8 + 4);
        }
        for (int t = 0; t < T_STEPS; ++t) {
            const int p = t & 1;
            f32x4 acc = {0,0,0,0};
            #pragma unroll
            for (int c = 0; c < 4; ++c) acc = mfma16(cvt8r(xst[2*c], xst[2*c+1]), WB[c], acc);

            __syncthreads();                   // BARR_A
            wait32(fr_dom, t + 1);
            const __bf16* rb = rhbuf + p * HB_P + i * (BT * H_DIM) + ln * H_DIM;
            bf16x8 rf[8];
            #pragma unroll
            for (int s = 0; s < 8; ++s) rf[s] = ld_frag16(rb + s * 32 + q * 8);
            #pragma unroll
            for (int s = 0; s < 8; ++s) acc = mfma16(rf[s], WB[4 + s], acc);
            #pragma unroll
            for (int r4 = 0; r4 < 4; ++r4) pL[q * 4 + r4][ln] = acc[r4];
            __syncthreads();                   // BARR_B (auto lgkm drain: pL visible)
            {
                const float* xp = xrow + (size_t)((t + 1 < T_STEPS) ? t + 1 : t) * I_DIM;
                #pragma unroll
                for (int c = 0; c < 4; ++c) {
                    xst[2*c]   = *(const float4*)(xp + c * 32 + q * 8);
                    xst[2*c+1] = *(const float4*)(xp + c * 32 + q * 8 + 4);
                }
            }
        }
    } else {
        // ============ wave 3: h~ high half (x 4-7, rh 16-23) + finisher ==========
        bf16x8 WB[12];
        #pragma unroll
        for (int c = 0; c < 4; ++c) {
            int krow = (4 + c) * 32 + q * 8;
            bf16x8 f;
            #pragma unroll
            for (int jj = 0; jj < 8; ++jj) f[jj] = (__bf16)Wh[(krow + jj) * H_DIM + cb + ln];
            WB[c] = f;
        }
        #pragma unroll
        for (int s = 0; s < 8; ++s) {
            int krow = (16 + s) * 32 + q * 8;
            bf16x8 f;
            #pragma unroll
            for (int jj = 0; jj < 8; ++jj) f[jj] = (__bf16)Wh[(krow + jj) * H_DIM + cb + ln];
            WB[4 + s] = f;
        }
        const float bc = bh[cb + ln];
        float hpv[4] = {0.0f, 0.0f, 0.0f, 0.0f};
        #pragma unroll
        for (int r4 = 0; r4 < 4; ++r4) hpL[q * 4 + r4][ln] = 0.0f;  // ordered by BARR_A(0)
        float4 xst[8];
        #pragma unroll
        for (int c = 0; c < 4; ++c) {
            xst[2*c]   = *(const float4*)(xrow + (4 + c) * 32 + q * 8);
            xst[2*c+1] = *(const float4*)(xrow + (4 + c) * 32 + q * 8 + 4);
        }
        for (int t = 0; t < T_STEPS; ++t) {
            const int p = t & 1;
            f32x4 acc = {0,0,0,0};
            #pragma unroll
            for (int c = 0; c < 4; ++c) acc = mfma16(cvt8r(xst[2*c], xst[2*c+1]), WB[c], acc);

            __syncthreads();                   // BARR_A
            wait32(fr_dom, t + 1);
            const __bf16* rb = rhbuf + p * HB_P + i * (BT * H_DIM) + ln * H_DIM;
            bf16x8 rf[8];
            #pragma unroll
            for (int s = 0; s < 8; ++s) rf[s] = ld_frag16(rb + (8 + s) * 32 + q * 8);
            #pragma unroll
            for (int s = 0; s < 8; ++s) acc = mfma16(rf[s], WB[4 + s], acc);
            __syncthreads();                   // BARR_B (z, pL now visible)

            __bf16* hbw = hbuf + p * HB_P + i * (BT * H_DIM);
            float hn4[4];
            #pragma unroll
            for (int r4 = 0; r4 < 4; ++r4) {
                int row = q * 4 + r4;
                float ph = acc[r4] + pL[row][ln] + bc;
                float e2 = __expf(2.0f * ph);
                float ht = (e2 - 1.0f) / (e2 + 1.0f);
                float zv = zL[row][ln];
                float hn = (1.0f - zv) * hpv[r4] + zv * ht;
                hpv[r4] = hn; hn4[r4] = hn;
                hpL[row][ln] = hn;
            }
            #pragma unroll
            for (int r4 = 0; r4 < 4; ++r4) {
                int row = q * 4 + r4;
                unsigned short v16 = __builtin_bit_cast(unsigned short, (__bf16)hn4[r4]);
                unsigned short nb  = (unsigned short)__shfl((int)v16, lane + 1);
                if (!(ln & 1))
                    st_u32((u32*)(hbw + row * H_DIM + cb + ln), (u32)v16 | ((u32)nb << 16));
            }
            drain_all();                       // h stores + hpL write hw-complete
            if (lane == 0) st_flag(my_fh, t + 1);
            #pragma unroll
            for (int r4 = 0; r4 < 4; ++r4) {   // off-critical-path output stores
                int row = q * 4 + r4;
                int bglob = i * BT + row;
                out[((size_t)bglob * T_STEPS + t) * H_DIM + cb + ln] = hn4[r4];
                if (t == T_STEPS - 1)
                    out[(size_t)B_TOT * T_STEPS * H_DIM + (size_t)bglob * H_DIM + cb + ln] = hn4[r4];
            }
            {
                const float* xp = xrow + (size_t)((t + 1 < T_STEPS) ? t + 1 : t) * I_DIM;
                #pragma unroll
                for (int c = 0; c < 4; ++c) {
                    xst[2*c]   = *(const float4*)(xp + (4 + c) * 32 + q * 8);
                    xst[2*c+1] = *(const float4*)(xp + (4 + c) * 32 + q * 8 + 4);
                }
            }
        }
    }
}

extern "C" void kernel_launch(void* const* d_in, const int* in_sizes, int n_in,
                              void* d_out, int out_size, void* d_ws, size_t ws_size,
                              hipStream_t stream)
{
    const float* xs = (const float*)d_in[0];
    const float* Wz = (const float*)d_in[1];
    const float* bz = (const float*)d_in[2];
    const float* Wr = (const float*)d_in[3];
    const float* br = (const float*)d_in[4];
    const float* Wh = (const float*)d_in[5];
    const float* bh = (const float*)d_in[6];
    float* out = (float*)d_out;

    // ws: hbuf[2][4][16][512] bf16 (128KB) | rhbuf (128KB) |
    //     flag_h[4][64] int (1KB) | flag_r[4][64] int (1KB)
    __bf16* hbuf  = (__bf16*)d_ws;
    __bf16* rhbuf = hbuf + 2 * HB_P;
    int* flag_h = (int*)((char*)d_ws + 262144);
    int* flag_r = flag_h + NBT * FDOM;

    hipMemsetAsync(d_ws, 0, 262144 + 2 * NBT * FDOM * 4, stream);
    gru_persist<<<dim3(NBT * NCT), dim3(256), 0, stream>>>(
        xs, Wz, bz, Wr, br, Wh, bh, out, hbuf, rhbuf, flag_h, flag_r);
}